// Round 1
// baseline (273.853 us; speedup 1.0000x reference)
//
#include <hip/hip_runtime.h>

// CTC loss forward, sum over batch. Linear-domain alpha recurrence with
// periodic exact power-of-2 rescaling (esum tracks the log-scale).
//
// Kernel A: compact + exponentiate emissions: ws[b][t][l] = exp(logp[t,b,ext[l]] + OFF)
// Kernel B: one wave per batch element; lane owns 4 consecutive trellis
//           positions; 2 shuffles/step; float4 emissions prefetched 16 deep.

constexpr int T = 1000, B = 32, C = 1000, S = 100;
constexpr int L = 2 * S + 1;      // 201
constexpr int RS = 204;           // padded row stride (floats), 16B-aligned rows
constexpr int RROWS = T + 16;     // pad rows so the 16-deep prefetch stays in-bounds
constexpr float OFF = 7.0f;       // emission log-offset: keeps per-step growth near 1.0
constexpr float LOG2E = 1.4426950408889634f;
constexpr float LN2 = 0.6931471805599453f;

// ---------------- Kernel A: staging ----------------
__global__ void stage_kernel(const float* __restrict__ logp,
                             const int* __restrict__ targets,
                             float* __restrict__ ws) {
    const int t = blockIdx.x;
    const int b = blockIdx.y;
    __shared__ float row[C];
    const float* src = logp + ((size_t)t * B + b) * C;
    const int tid = threadIdx.x;
    if (tid < C / 4) {
        ((float4*)row)[tid] = ((const float4*)src)[tid];
    }
    __syncthreads();
    if (tid < RS) {
        float p;
        if (tid < L) {
            const int c = (tid & 1) ? targets[b * S + (tid >> 1)] : 0;
            p = exp2f((row[c] + OFF) * LOG2E);
        } else {
            p = 0.0f;  // pad columns 201..203 -> dead
        }
        ws[((size_t)b * RROWS + t) * RS + tid] = p;
    }
}

// ---------------- Kernel B: recurrence ----------------
__global__ void __launch_bounds__(64) ctc_kernel(const float* __restrict__ ws,
                                                 const int* __restrict__ targets,
                                                 const int* __restrict__ input_lens,
                                                 const int* __restrict__ target_lens,
                                                 float* __restrict__ out) {
    const int b = blockIdx.x;
    const int lane = threadIdx.x;
    // lanes 0..50 own positions 4*lane..4*lane+3; lanes 51..63 are dead (clamped col)
    const int col = (lane <= 50) ? 4 * lane : 200;
    const int Tb = input_lens[b];
    const int tl = target_lens[b];
    const float* pw = ws + (size_t)b * RROWS * RS;

    // skip-transition masks for my 4 positions (constant over t)
    float m0 = 0.f, m1 = 0.f, m2 = 0.f, m3 = 0.f;
    {
        float mm[4];
#pragma unroll
        for (int i = 0; i < 4; ++i) {
            const int l = col + i;
            float mk = 0.f;
            if ((lane <= 50) && (l & 1) && l >= 3 && l < L) {
                const int s = (l - 1) >> 1;
                if (targets[b * S + s] != targets[b * S + s - 1]) mk = 1.f;
            }
            mm[i] = mk;
        }
        m0 = mm[0]; m1 = mm[1]; m2 = mm[2]; m3 = mm[3];
    }
    // interior lanes receive neighbor alphas; lane 0 and dead lanes get zeros
    const bool interior = (lane > 0) && (lane <= 50);

    // init at t=0: alpha[0] = p(blank), alpha[1] = p(tgt0), rest 0
    float a0 = 0.f, a1 = 0.f, a2 = 0.f, a3 = 0.f;
    {
        const float4 p0 = *(const float4*)(pw + col);
        if (lane == 0) { a0 = p0.x; a1 = p0.y; }
    }
    int esum = 0;

#define CTC_STEP(P_)                                        \
    do {                                                    \
        float am1 = __shfl_up(a3, 1);                       \
        float am2 = __shfl_up(a2, 1);                       \
        am1 = interior ? am1 : 0.f;                         \
        am2 = interior ? am2 : 0.f;                         \
        const float n0 = (a0 + am1 + am2 * m0) * (P_).x;    \
        const float n1 = (a1 + a0 + am1 * m1) * (P_).y;     \
        const float n2 = (a2 + a1 + a0 * m2) * (P_).z;      \
        const float n3 = (a3 + a2 + a1 * m3) * (P_).w;      \
        a0 = n0; a1 = n1; a2 = n2; a3 = n3;                 \
    } while (0)

    // prefetch ring: P[i] holds emission row for step t+i
    float4 P[16];
    {
        const float* pf0 = pw + (size_t)RS + col;
#pragma unroll
        for (int i = 0; i < 16; ++i) P[i] = *(const float4*)(pf0 + (size_t)i * RS);
    }
    const float* pf = pw + (size_t)17 * RS + col;  // next row to prefetch

    int t = 1;
    while (t + 16 <= Tb) {
#pragma unroll
        for (int i = 0; i < 16; ++i) {
            const float4 p = P[i];
            P[i] = *(const float4*)pf;   // prefetch 16 steps ahead
            pf += RS;
            CTC_STEP(p);
        }
        // rescale every 16 steps: divide by 2^e (exact), accumulate e
        float mx = fmaxf(fmaxf(a0, a1), fmaxf(a2, a3));
#pragma unroll
        for (int off = 32; off; off >>= 1) mx = fmaxf(mx, __shfl_xor(mx, off));
        if (mx > 0.f) {
            const int e = ilogbf(mx);
            const float sc = ldexpf(1.0f, -e);
            a0 *= sc; a1 *= sc; a2 *= sc; a3 *= sc;
            esum += e;
        }
        t += 16;
    }
    // tail (< 16 steps), uniform predicate
    {
        const int rem = Tb - t;  // steps remaining: t..Tb-1
#pragma unroll
        for (int i = 0; i < 16; ++i) {
            if (i < rem) {
                const float4 p = P[i];
                CTC_STEP(p);
            }
        }
    }
#undef CTC_STEP

    // final: sum alpha at positions 2*tl and 2*tl-1
    const int e1 = 2 * tl, e2 = 2 * tl - 1;
    float contrib = 0.f;
    if (lane <= 50) {
        if (col + 0 == e1 || col + 0 == e2) contrib += a0;
        if (col + 1 == e1 || col + 1 == e2) contrib += a1;
        if (col + 2 == e1 || col + 2 == e2) contrib += a2;
        if (col + 3 == e1 || col + 3 == e2) contrib += a3;
    }
#pragma unroll
    for (int off = 32; off; off >>= 1) contrib += __shfl_xor(contrib, off);

    if (lane == 0) {
        const float logalpha = logf(contrib) + (float)esum * LN2 - OFF * (float)Tb;
        float loss = -logalpha;
        if (!(loss < 0.5e30f)) loss = 0.f;  // zero_infinity (also catches NaN/inf)
        atomicAdd(out, loss);
    }
}

// ---------------- Fallback: direct gather (if ws too small) ----------------
__global__ void __launch_bounds__(64) ctc_direct_kernel(const float* __restrict__ logp,
                                                        const int* __restrict__ targets,
                                                        const int* __restrict__ input_lens,
                                                        const int* __restrict__ target_lens,
                                                        float* __restrict__ out) {
    const int b = blockIdx.x;
    const int lane = threadIdx.x;
    const int col = (lane <= 50) ? 4 * lane : 200;
    const int Tb = input_lens[b];
    const int tl = target_lens[b];

    int cc[4]; float mm[4], pm[4];
#pragma unroll
    for (int i = 0; i < 4; ++i) {
        const int l = col + i;
        const bool real = (lane <= 50) && (l < L);
        pm[i] = real ? 1.f : 0.f;
        cc[i] = real ? ((l & 1) ? targets[b * S + (l >> 1)] : 0) : 0;
        float mk = 0.f;
        if (real && (l & 1) && l >= 3) {
            const int s = (l - 1) >> 1;
            if (targets[b * S + s] != targets[b * S + s - 1]) mk = 1.f;
        }
        mm[i] = mk;
    }
    const float m0 = mm[0], m1 = mm[1], m2 = mm[2], m3 = mm[3];
    const bool interior = (lane > 0) && (lane <= 50);

    float a0 = 0.f, a1 = 0.f, a2 = 0.f, a3 = 0.f;
    {
        const float* rowp = logp + (size_t)b * C;
        const float p0 = pm[0] * exp2f((rowp[cc[0]] + OFF) * LOG2E);
        const float p1 = pm[1] * exp2f((rowp[cc[1]] + OFF) * LOG2E);
        if (lane == 0) { a0 = p0; a1 = p1; }
    }
    int esum = 0;

    for (int t = 1; t < Tb; ++t) {
        const float* rowp = logp + ((size_t)t * B + b) * C;
        const float p0 = pm[0] * exp2f((rowp[cc[0]] + OFF) * LOG2E);
        const float p1 = pm[1] * exp2f((rowp[cc[1]] + OFF) * LOG2E);
        const float p2 = pm[2] * exp2f((rowp[cc[2]] + OFF) * LOG2E);
        const float p3 = pm[3] * exp2f((rowp[cc[3]] + OFF) * LOG2E);
        float am1 = __shfl_up(a3, 1);
        float am2 = __shfl_up(a2, 1);
        am1 = interior ? am1 : 0.f;
        am2 = interior ? am2 : 0.f;
        const float n0 = (a0 + am1 + am2 * m0) * p0;
        const float n1 = (a1 + a0 + am1 * m1) * p1;
        const float n2 = (a2 + a1 + a0 * m2) * p2;
        const float n3 = (a3 + a2 + a1 * m3) * p3;
        a0 = n0; a1 = n1; a2 = n2; a3 = n3;
        if ((t & 15) == 0) {
            float mx = fmaxf(fmaxf(a0, a1), fmaxf(a2, a3));
#pragma unroll
            for (int off = 32; off; off >>= 1) mx = fmaxf(mx, __shfl_xor(mx, off));
            if (mx > 0.f) {
                const int e = ilogbf(mx);
                const float sc = ldexpf(1.0f, -e);
                a0 *= sc; a1 *= sc; a2 *= sc; a3 *= sc;
                esum += e;
            }
        }
    }

    const int e1 = 2 * tl, e2 = 2 * tl - 1;
    float contrib = 0.f;
    if (lane <= 50) {
        if (col + 0 == e1 || col + 0 == e2) contrib += a0;
        if (col + 1 == e1 || col + 1 == e2) contrib += a1;
        if (col + 2 == e1 || col + 2 == e2) contrib += a2;
        if (col + 3 == e1 || col + 3 == e2) contrib += a3;
    }
#pragma unroll
    for (int off = 32; off; off >>= 1) contrib += __shfl_xor(contrib, off);
    if (lane == 0) {
        const float logalpha = logf(contrib) + (float)esum * LN2 - OFF * (float)Tb;
        float loss = -logalpha;
        if (!(loss < 0.5e30f)) loss = 0.f;
        atomicAdd(out, loss);
    }
}

extern "C" void kernel_launch(void* const* d_in, const int* in_sizes, int n_in,
                              void* d_out, int out_size, void* d_ws, size_t ws_size,
                              hipStream_t stream) {
    const float* logp = (const float*)d_in[0];
    const int* targets = (const int*)d_in[1];
    const int* input_lens = (const int*)d_in[2];
    const int* target_lens = (const int*)d_in[3];
    float* out = (float*)d_out;
    float* ws = (float*)d_ws;

    hipMemsetAsync(d_out, 0, sizeof(float), stream);

    const size_t ws_needed = (size_t)B * RROWS * RS * sizeof(float);
    if (ws_size >= ws_needed) {
        dim3 gA(T, B);
        stage_kernel<<<gA, 256, 0, stream>>>(logp, targets, ws);
        ctc_kernel<<<B, 64, 0, stream>>>(ws, targets, input_lens, target_lens, out);
    } else {
        ctc_direct_kernel<<<B, 64, 0, stream>>>(logp, targets, input_lens, target_lens, out);
    }
}

// Round 2
// 243.545 us; speedup vs baseline: 1.1244x; 1.1244x over previous
//
#include <hip/hip_runtime.h>

// CTC loss forward, sum over batch. Linear-domain alpha recurrence with
// periodic exact power-of-2 rescaling (esum tracks the log-scale).
//
// Kernel A: compact + exponentiate emissions: ws[b][t][l] = exp(logp[t,b,ext[l]] + OFF)
// Kernel B: one wave per batch element; lane owns 4 consecutive trellis
//           positions; cross-lane via DPP wave_shr:1 (VALU latency, not LDS);
//           float4 emissions prefetched 16 deep; DPP-ladder max for rescale.

constexpr int T = 1000, B = 32, C = 1000, S = 100;
constexpr int L = 2 * S + 1;      // 201
constexpr int RS = 204;           // padded row stride (floats), 16B-aligned rows
constexpr int RROWS = T + 16;     // pad rows so the 16-deep prefetch stays in-bounds
constexpr float OFF = 7.0f;       // emission log-offset: keeps per-step growth near 1.0
constexpr float LOG2E = 1.4426950408889634f;
constexpr float LN2 = 0.6931471805599453f;

// DPP wave_shr:1 — lane i reads lane i-1; lane 0 gets 0 (bound_ctrl).
__device__ __forceinline__ float dpp_shr1(float x) {
    return __int_as_float(
        __builtin_amdgcn_update_dpp(0, __float_as_int(x), 0x138, 0xF, 0xF, true));
}

// Wave-wide max of NONNEGATIVE values via gfx9 DPP ladder; result uniform (SGPR).
__device__ __forceinline__ float wave_max_nonneg(float x) {
#define DPP_MAX(ctrl)                                                        \
    x = fmaxf(x, __int_as_float(__builtin_amdgcn_update_dpp(                 \
                     0, __float_as_int(x), (ctrl), 0xF, 0xF, true)))
    DPP_MAX(0x111);  // row_shr:1
    DPP_MAX(0x112);  // row_shr:2
    DPP_MAX(0x114);  // row_shr:4
    DPP_MAX(0x118);  // row_shr:8  -> lane15/31/47/63 hold 16-lane maxes
    DPP_MAX(0x142);  // row_bcast15 -> lane31/63 hold 32-lane maxes
    DPP_MAX(0x143);  // row_bcast31 -> lane63 holds wave max
#undef DPP_MAX
    return __int_as_float(__builtin_amdgcn_readlane(__float_as_int(x), 63));
}

// ---------------- Kernel A: staging ----------------
__global__ void stage_kernel(const float* __restrict__ logp,
                             const int* __restrict__ targets,
                             float* __restrict__ ws) {
    const int t = blockIdx.x;
    const int b = blockIdx.y;
    __shared__ float row[C];
    const float* src = logp + ((size_t)t * B + b) * C;
    const int tid = threadIdx.x;
    if (tid < C / 4) {
        ((float4*)row)[tid] = ((const float4*)src)[tid];
    }
    __syncthreads();
    if (tid < RS) {
        float p;
        if (tid < L) {
            const int c = (tid & 1) ? targets[b * S + (tid >> 1)] : 0;
            p = exp2f((row[c] + OFF) * LOG2E);
        } else {
            p = 0.0f;  // pad columns 201..203 -> dead (keeps lane-50 a1..a3 == 0)
        }
        ws[((size_t)b * RROWS + t) * RS + tid] = p;
    }
}

// ---------------- Kernel B: recurrence ----------------
__global__ void __launch_bounds__(64) ctc_kernel(const float* __restrict__ ws,
                                                 const int* __restrict__ targets,
                                                 const int* __restrict__ input_lens,
                                                 const int* __restrict__ target_lens,
                                                 float* __restrict__ out) {
    const int b = blockIdx.x;
    const int lane = threadIdx.x;
    // lanes 0..50 own positions 4*lane..4*lane+3; lanes 51..63 are dead (clamped col)
    const int col = (lane <= 50) ? 4 * lane : 200;
    const int Tb = input_lens[b];
    const int tl = target_lens[b];
    const float* pw = ws + (size_t)b * RROWS * RS;

    // Skip-transition masks. Even positions are blanks -> no skip ever, so only
    // the two odd positions (col+1, col+3) need masks.
    float m1 = 0.f, m3 = 0.f;
    if (lane <= 50) {
        const int l1 = col + 1;  // odd
        if (l1 >= 3 && l1 < L) {
            const int s = (l1 - 1) >> 1;
            if (targets[b * S + s] != targets[b * S + s - 1]) m1 = 1.f;
        }
        const int l3 = col + 3;  // odd
        if (l3 >= 3 && l3 < L) {
            const int s = (l3 - 1) >> 1;
            if (targets[b * S + s] != targets[b * S + s - 1]) m3 = 1.f;
        }
    }

    // init at t=0: alpha[0] = p(blank), alpha[1] = p(tgt0), rest 0
    float a0 = 0.f, a1 = 0.f, a2 = 0.f, a3 = 0.f;
    {
        const float4 p0 = *(const float4*)(pw + col);
        if (lane == 0) { a0 = p0.x; a1 = p0.y; }
    }
    int esum = 0;

    // Dead-lane invariant: lane 50's p.y/z/w are the 0-padded columns, so its
    // a1,a2,a3 stay exactly 0; lanes 51+ therefore receive zeros via DPP and
    // stay 0. Lane 0 receives 0 via bound_ctrl. No masking needed in the step.
#define CTC_STEP(P_)                                              \
    do {                                                          \
        const float am1 = dpp_shr1(a3);                           \
        const float am2 = dpp_shr1(a2);                           \
        const float q1 = m1 * (P_).y;                             \
        const float q3 = m3 * (P_).w;                             \
        const float n0 = fmaf(am1, (P_).x, a0 * (P_).x);          \
        const float n1 = fmaf(am1, q1, fmaf(a0, (P_).y, a1 * (P_).y)); \
        const float n2 = fmaf(a1, (P_).z, a2 * (P_).z);           \
        const float n3 = fmaf(a1, q3, fmaf(a2, (P_).w, a3 * (P_).w)); \
        (void)am2;                                                \
        a0 = n0; a1 = n1; a2 = n2; a3 = n3;                       \
    } while (0)
    // NOTE: am2 (skip source, position col-2) feeds n0 only when position col
    // is odd — but col is even (4*lane), so the n0 skip term is always 0 and
    // am2 is unused. Kept computed-then-discarded for clarity; compiler DCEs it.

    // prefetch ring: P[i] holds emission row for step t+i
    float4 P[16];
    {
        const float* pf0 = pw + (size_t)RS + col;
#pragma unroll
        for (int i = 0; i < 16; ++i) P[i] = *(const float4*)(pf0 + (size_t)i * RS);
    }
    const float* pf = pw + (size_t)17 * RS + col;  // next row to prefetch

    int t = 1;
    while (t + 16 <= Tb) {
#pragma unroll
        for (int i = 0; i < 16; ++i) {
            const float4 p = P[i];
            P[i] = *(const float4*)pf;   // prefetch 16 steps ahead
            pf += RS;
            CTC_STEP(p);
        }
        // rescale every 16 steps: divide by 2^e (exact), accumulate e
        const float mx = wave_max_nonneg(fmaxf(fmaxf(a0, a1), fmaxf(a2, a3)));
        const unsigned bits = __float_as_uint(mx);
        if (bits != 0u) {
            const int e = (int)((bits >> 23) & 0xFFu) - 127;  // ilogb (denorm->-127, ok)
            const float sc = __uint_as_float((unsigned)(127 - e) << 23);  // 2^-e exact
            a0 *= sc; a1 *= sc; a2 *= sc; a3 *= sc;
            esum += e;
        }
        t += 16;
    }
    // tail (< 16 steps), uniform predicate
    {
        const int rem = Tb - t;  // steps remaining: t..Tb-1
#pragma unroll
        for (int i = 0; i < 16; ++i) {
            if (i < rem) {
                const float4 p = P[i];
                CTC_STEP(p);
            }
        }
    }
#undef CTC_STEP

    // final: sum alpha at positions 2*tl and 2*tl-1
    const int e1 = 2 * tl, e2 = 2 * tl - 1;
    float contrib = 0.f;
    if (lane <= 50) {
        if (col + 0 == e1 || col + 0 == e2) contrib += a0;
        if (col + 1 == e1 || col + 1 == e2) contrib += a1;
        if (col + 2 == e1 || col + 2 == e2) contrib += a2;
        if (col + 3 == e1 || col + 3 == e2) contrib += a3;
    }
#pragma unroll
    for (int off = 32; off; off >>= 1) contrib += __shfl_xor(contrib, off);

    if (lane == 0) {
        const float logalpha = logf(contrib) + (float)esum * LN2 - OFF * (float)Tb;
        float loss = -logalpha;
        if (!(loss < 0.5e30f)) loss = 0.f;  // zero_infinity (also catches NaN/inf)
        atomicAdd(out, loss);
    }
}

// ---------------- Fallback: direct gather (if ws too small) ----------------
__global__ void __launch_bounds__(64) ctc_direct_kernel(const float* __restrict__ logp,
                                                        const int* __restrict__ targets,
                                                        const int* __restrict__ input_lens,
                                                        const int* __restrict__ target_lens,
                                                        float* __restrict__ out) {
    const int b = blockIdx.x;
    const int lane = threadIdx.x;
    const int col = (lane <= 50) ? 4 * lane : 200;
    const int Tb = input_lens[b];
    const int tl = target_lens[b];

    int cc[4]; float mm[4], pm[4];
#pragma unroll
    for (int i = 0; i < 4; ++i) {
        const int l = col + i;
        const bool real = (lane <= 50) && (l < L);
        pm[i] = real ? 1.f : 0.f;
        cc[i] = real ? ((l & 1) ? targets[b * S + (l >> 1)] : 0) : 0;
        float mk = 0.f;
        if (real && (l & 1) && l >= 3) {
            const int s = (l - 1) >> 1;
            if (targets[b * S + s] != targets[b * S + s - 1]) mk = 1.f;
        }
        mm[i] = mk;
    }
    const float m1 = mm[1], m3 = mm[3];

    float a0 = 0.f, a1 = 0.f, a2 = 0.f, a3 = 0.f;
    {
        const float* rowp = logp + (size_t)b * C;
        const float p0 = pm[0] * exp2f((rowp[cc[0]] + OFF) * LOG2E);
        const float p1 = pm[1] * exp2f((rowp[cc[1]] + OFF) * LOG2E);
        if (lane == 0) { a0 = p0; a1 = p1; }
    }
    int esum = 0;

    for (int t = 1; t < Tb; ++t) {
        const float* rowp = logp + ((size_t)t * B + b) * C;
        const float p0 = pm[0] * exp2f((rowp[cc[0]] + OFF) * LOG2E);
        const float p1 = pm[1] * exp2f((rowp[cc[1]] + OFF) * LOG2E);
        const float p2 = pm[2] * exp2f((rowp[cc[2]] + OFF) * LOG2E);
        const float p3 = pm[3] * exp2f((rowp[cc[3]] + OFF) * LOG2E);
        const float am1 = dpp_shr1(a3);
        const float q1 = m1 * p1;
        const float q3 = m3 * p3;
        const float n0 = fmaf(am1, p0, a0 * p0);
        const float n1 = fmaf(am1, q1, fmaf(a0, p1, a1 * p1));
        const float n2 = fmaf(a1, p2, a2 * p2);
        const float n3 = fmaf(a1, q3, fmaf(a2, p3, a3 * p3));
        a0 = n0; a1 = n1; a2 = n2; a3 = n3;
        if ((t & 15) == 0) {
            const float mx = wave_max_nonneg(fmaxf(fmaxf(a0, a1), fmaxf(a2, a3)));
            const unsigned bits = __float_as_uint(mx);
            if (bits != 0u) {
                const int e = (int)((bits >> 23) & 0xFFu) - 127;
                const float sc = __uint_as_float((unsigned)(127 - e) << 23);
                a0 *= sc; a1 *= sc; a2 *= sc; a3 *= sc;
                esum += e;
            }
        }
    }

    const int e1 = 2 * tl, e2 = 2 * tl - 1;
    float contrib = 0.f;
    if (lane <= 50) {
        if (col + 0 == e1 || col + 0 == e2) contrib += a0;
        if (col + 1 == e1 || col + 1 == e2) contrib += a1;
        if (col + 2 == e1 || col + 2 == e2) contrib += a2;
        if (col + 3 == e1 || col + 3 == e2) contrib += a3;
    }
#pragma unroll
    for (int off = 32; off; off >>= 1) contrib += __shfl_xor(contrib, off);
    if (lane == 0) {
        const float logalpha = logf(contrib) + (float)esum * LN2 - OFF * (float)Tb;
        float loss = -logalpha;
        if (!(loss < 0.5e30f)) loss = 0.f;
        atomicAdd(out, loss);
    }
}

extern "C" void kernel_launch(void* const* d_in, const int* in_sizes, int n_in,
                              void* d_out, int out_size, void* d_ws, size_t ws_size,
                              hipStream_t stream) {
    const float* logp = (const float*)d_in[0];
    const int* targets = (const int*)d_in[1];
    const int* input_lens = (const int*)d_in[2];
    const int* target_lens = (const int*)d_in[3];
    float* out = (float*)d_out;
    float* ws = (float*)d_ws;

    hipMemsetAsync(d_out, 0, sizeof(float), stream);

    const size_t ws_needed = (size_t)B * RROWS * RS * sizeof(float);
    if (ws_size >= ws_needed) {
        dim3 gA(T, B);
        stage_kernel<<<gA, 256, 0, stream>>>(logp, targets, ws);
        ctc_kernel<<<B, 64, 0, stream>>>(ws, targets, input_lens, target_lens, out);
    } else {
        ctc_direct_kernel<<<B, 64, 0, stream>>>(logp, targets, input_lens, target_lens, out);
    }
}

// Round 3
// 236.105 us; speedup vs baseline: 1.1599x; 1.0315x over previous
//
#include <hip/hip_runtime.h>

// CTC loss forward, sum over batch. Linear-domain alpha recurrence with
// periodic exact power-of-2 rescaling (esum tracks the log-scale).
//
// Kernel A: compact + exponentiate emissions: ws[b][t][l] = exp(logp[t,b,ext[l]] + OFF)
// Kernel B: one wave per batch element; lane owns 4 consecutive trellis
//           positions; cross-lane via DPP wave_shr:1; float4 emissions
//           prefetched 32 deep (memory-latency cover ~900cyc/32); add-form
//           step = 11 VALU/step.

constexpr int T = 1000, B = 32, C = 1000, S = 100;
constexpr int L = 2 * S + 1;      // 201
constexpr int RS = 204;           // padded row stride (floats), 16B-aligned rows
constexpr int PFD = 32;           // prefetch depth
constexpr int RROWS = T + PFD;    // pad rows so the prefetch stays in-bounds
constexpr float OFF = 7.0f;       // emission log-offset: keeps per-step growth near 1.0
constexpr float LOG2E = 1.4426950408889634f;
constexpr float LN2 = 0.6931471805599453f;

// DPP wave_shr:1 — lane i reads lane i-1; lane 0 gets 0 (bound_ctrl).
__device__ __forceinline__ float dpp_shr1(float x) {
    return __int_as_float(
        __builtin_amdgcn_update_dpp(0, __float_as_int(x), 0x138, 0xF, 0xF, true));
}

// Wave-wide max of NONNEGATIVE values via gfx9 DPP ladder; result uniform (SGPR).
__device__ __forceinline__ float wave_max_nonneg(float x) {
#define DPP_MAX(ctrl)                                                        \
    x = fmaxf(x, __int_as_float(__builtin_amdgcn_update_dpp(                 \
                     0, __float_as_int(x), (ctrl), 0xF, 0xF, true)))
    DPP_MAX(0x111);  // row_shr:1
    DPP_MAX(0x112);  // row_shr:2
    DPP_MAX(0x114);  // row_shr:4
    DPP_MAX(0x118);  // row_shr:8  -> lane15/31/47/63 hold 16-lane maxes
    DPP_MAX(0x142);  // row_bcast15 -> lane31/63 hold 32-lane maxes
    DPP_MAX(0x143);  // row_bcast31 -> lane63 holds wave max
#undef DPP_MAX
    return __int_as_float(__builtin_amdgcn_readlane(__float_as_int(x), 63));
}

// ---------------- Kernel A: staging ----------------
__global__ void stage_kernel(const float* __restrict__ logp,
                             const int* __restrict__ targets,
                             float* __restrict__ ws) {
    const int t = blockIdx.x;
    const int b = blockIdx.y;
    __shared__ float row[C];
    const float* src = logp + ((size_t)t * B + b) * C;
    const int tid = threadIdx.x;
    if (tid < C / 4) {
        ((float4*)row)[tid] = ((const float4*)src)[tid];
    }
    __syncthreads();
    if (tid < RS) {
        float p;
        if (tid < L) {
            const int c = (tid & 1) ? targets[b * S + (tid >> 1)] : 0;
            p = exp2f((row[c] + OFF) * LOG2E);
        } else {
            p = 0.0f;  // pad columns 201..203 -> dead (keeps lane-50 a1..a3 == 0)
        }
        ws[((size_t)b * RROWS + t) * RS + tid] = p;
    }
}

// ---------------- Kernel B: recurrence ----------------
__global__ void __launch_bounds__(64) ctc_kernel(const float* __restrict__ ws,
                                                 const int* __restrict__ targets,
                                                 const int* __restrict__ input_lens,
                                                 const int* __restrict__ target_lens,
                                                 float* __restrict__ out) {
    const int b = blockIdx.x;
    const int lane = threadIdx.x;
    // lanes 0..50 own positions 4*lane..4*lane+3; lanes 51..63 are dead (clamped col)
    const int col = (lane <= 50) ? 4 * lane : 200;
    const int Tb = input_lens[b];
    const int tl = target_lens[b];
    const float* pw = ws + (size_t)b * RROWS * RS;

    // Skip-transition masks. Even positions are blanks -> no skip ever, so only
    // the two odd positions (col+1, col+3) need masks.
    float m1 = 0.f, m3 = 0.f;
    if (lane <= 50) {
        const int l1 = col + 1;  // odd
        if (l1 >= 3 && l1 < L) {
            const int s = (l1 - 1) >> 1;
            if (targets[b * S + s] != targets[b * S + s - 1]) m1 = 1.f;
        }
        const int l3 = col + 3;  // odd
        if (l3 >= 3 && l3 < L) {
            const int s = (l3 - 1) >> 1;
            if (targets[b * S + s] != targets[b * S + s - 1]) m3 = 1.f;
        }
    }

    // init at t=0: alpha[0] = p(blank), alpha[1] = p(tgt0), rest 0
    float a0 = 0.f, a1 = 0.f, a2 = 0.f, a3 = 0.f;
    {
        const float4 p0 = *(const float4*)(pw + col);
        if (lane == 0) { a0 = p0.x; a1 = p0.y; }
    }
    int esum = 0;

    // Dead-lane invariant: lane 50's p.y/z/w are the 0-padded columns, so its
    // a1,a2,a3 stay exactly 0; lanes 51+ therefore receive zeros via DPP and
    // stay 0. Lane 0 receives 0 via bound_ctrl. No masking needed in the step.
    // Even positions (col, col+2) are blanks -> no skip term; odd positions use
    // precomputed masks m1/m3. Add-form: 1 DPP + 10 VALU per step.
#define CTC_STEP(P_)                                  \
    do {                                              \
        const float am1 = dpp_shr1(a3);               \
        const float s01 = a0 + a1;                    \
        const float s23 = a2 + a3;                    \
        const float n0 = (a0 + am1) * (P_).x;         \
        const float n1 = fmaf(am1, m1, s01) * (P_).y; \
        const float n2 = (a1 + a2) * (P_).z;          \
        const float n3 = fmaf(a1, m3, s23) * (P_).w;  \
        a0 = n0; a1 = n1; a2 = n2; a3 = n3;           \
    } while (0)

#define CTC_RESCALE()                                                          \
    do {                                                                       \
        const float mx = wave_max_nonneg(fmaxf(fmaxf(a0, a1), fmaxf(a2, a3))); \
        const unsigned bits = __float_as_uint(mx);                             \
        if (bits != 0u) {                                                      \
            const int e = (int)((bits >> 23) & 0xFFu) - 127;                   \
            const float sc = __uint_as_float((unsigned)(127 - e) << 23);       \
            a0 *= sc; a1 *= sc; a2 *= sc; a3 *= sc;                            \
            esum += e;                                                         \
        }                                                                      \
    } while (0)

    // prefetch ring: P[i] holds emission row for step t+i
    float4 P[PFD];
    {
        const float* pf0 = pw + (size_t)RS + col;
#pragma unroll
        for (int i = 0; i < PFD; ++i) P[i] = *(const float4*)(pf0 + (size_t)i * RS);
    }
    const float* pf = pw + (size_t)(PFD + 1) * RS + col;  // next row to prefetch

    int t = 1;
    while (t + PFD <= Tb) {
#pragma unroll
        for (int i = 0; i < PFD; ++i) {
            const float4 p = P[i];
            P[i] = *(const float4*)pf;   // prefetch PFD steps ahead
            pf += RS;
            CTC_STEP(p);
            if (i == 15) CTC_RESCALE();  // keep 16-step rescale cadence
        }
        CTC_RESCALE();
        t += PFD;
    }
    // tail (< PFD steps), uniform predicate; growth over <=31 steps is safe
    {
        const int rem = Tb - t;  // steps remaining: t..Tb-1
#pragma unroll
        for (int i = 0; i < PFD; ++i) {
            if (i < rem) {
                const float4 p = P[i];
                CTC_STEP(p);
            }
        }
    }
#undef CTC_STEP

    // final: sum alpha at positions 2*tl and 2*tl-1
    const int e1 = 2 * tl, e2 = 2 * tl - 1;
    float contrib = 0.f;
    if (lane <= 50) {
        if (col + 0 == e1 || col + 0 == e2) contrib += a0;
        if (col + 1 == e1 || col + 1 == e2) contrib += a1;
        if (col + 2 == e1 || col + 2 == e2) contrib += a2;
        if (col + 3 == e1 || col + 3 == e2) contrib += a3;
    }
#pragma unroll
    for (int off = 32; off; off >>= 1) contrib += __shfl_xor(contrib, off);

    if (lane == 0) {
        const float logalpha = logf(contrib) + (float)esum * LN2 - OFF * (float)Tb;
        float loss = -logalpha;
        if (!(loss < 0.5e30f)) loss = 0.f;  // zero_infinity (also catches NaN/inf)
        atomicAdd(out, loss);
    }
}

// ---------------- Fallback: direct gather (if ws too small) ----------------
__global__ void __launch_bounds__(64) ctc_direct_kernel(const float* __restrict__ logp,
                                                        const int* __restrict__ targets,
                                                        const int* __restrict__ input_lens,
                                                        const int* __restrict__ target_lens,
                                                        float* __restrict__ out) {
    const int b = blockIdx.x;
    const int lane = threadIdx.x;
    const int col = (lane <= 50) ? 4 * lane : 200;
    const int Tb = input_lens[b];
    const int tl = target_lens[b];

    int cc[4]; float mm[4], pm[4];
#pragma unroll
    for (int i = 0; i < 4; ++i) {
        const int l = col + i;
        const bool real = (lane <= 50) && (l < L);
        pm[i] = real ? 1.f : 0.f;
        cc[i] = real ? ((l & 1) ? targets[b * S + (l >> 1)] : 0) : 0;
        float mk = 0.f;
        if (real && (l & 1) && l >= 3) {
            const int s = (l - 1) >> 1;
            if (targets[b * S + s] != targets[b * S + s - 1]) mk = 1.f;
        }
        mm[i] = mk;
    }
    const float m1 = mm[1], m3 = mm[3];

    float a0 = 0.f, a1 = 0.f, a2 = 0.f, a3 = 0.f;
    {
        const float* rowp = logp + (size_t)b * C;
        const float p0 = pm[0] * exp2f((rowp[cc[0]] + OFF) * LOG2E);
        const float p1 = pm[1] * exp2f((rowp[cc[1]] + OFF) * LOG2E);
        if (lane == 0) { a0 = p0; a1 = p1; }
    }
    int esum = 0;

    for (int t = 1; t < Tb; ++t) {
        const float* rowp = logp + ((size_t)t * B + b) * C;
        const float p0 = pm[0] * exp2f((rowp[cc[0]] + OFF) * LOG2E);
        const float p1 = pm[1] * exp2f((rowp[cc[1]] + OFF) * LOG2E);
        const float p2 = pm[2] * exp2f((rowp[cc[2]] + OFF) * LOG2E);
        const float p3 = pm[3] * exp2f((rowp[cc[3]] + OFF) * LOG2E);
        const float am1 = dpp_shr1(a3);
        const float n0 = (a0 + am1) * p0;
        const float n1 = fmaf(am1, m1, a0 + a1) * p1;
        const float n2 = (a1 + a2) * p2;
        const float n3 = fmaf(a1, m3, a2 + a3) * p3;
        a0 = n0; a1 = n1; a2 = n2; a3 = n3;
        if ((t & 15) == 0) {
            const float mx = wave_max_nonneg(fmaxf(fmaxf(a0, a1), fmaxf(a2, a3)));
            const unsigned bits = __float_as_uint(mx);
            if (bits != 0u) {
                const int e = (int)((bits >> 23) & 0xFFu) - 127;
                const float sc = __uint_as_float((unsigned)(127 - e) << 23);
                a0 *= sc; a1 *= sc; a2 *= sc; a3 *= sc;
                esum += e;
            }
        }
    }

    const int e1 = 2 * tl, e2 = 2 * tl - 1;
    float contrib = 0.f;
    if (lane <= 50) {
        if (col + 0 == e1 || col + 0 == e2) contrib += a0;
        if (col + 1 == e1 || col + 1 == e2) contrib += a1;
        if (col + 2 == e1 || col + 2 == e2) contrib += a2;
        if (col + 3 == e1 || col + 3 == e2) contrib += a3;
    }
#pragma unroll
    for (int off = 32; off; off >>= 1) contrib += __shfl_xor(contrib, off);
    if (lane == 0) {
        const float logalpha = logf(contrib) + (float)esum * LN2 - OFF * (float)Tb;
        float loss = -logalpha;
        if (!(loss < 0.5e30f)) loss = 0.f;
        atomicAdd(out, loss);
    }
}

extern "C" void kernel_launch(void* const* d_in, const int* in_sizes, int n_in,
                              void* d_out, int out_size, void* d_ws, size_t ws_size,
                              hipStream_t stream) {
    const float* logp = (const float*)d_in[0];
    const int* targets = (const int*)d_in[1];
    const int* input_lens = (const int*)d_in[2];
    const int* target_lens = (const int*)d_in[3];
    float* out = (float*)d_out;
    float* ws = (float*)d_ws;

    hipMemsetAsync(d_out, 0, sizeof(float), stream);

    const size_t ws_needed = (size_t)B * RROWS * RS * sizeof(float);
    if (ws_size >= ws_needed) {
        dim3 gA(T, B);
        stage_kernel<<<gA, 256, 0, stream>>>(logp, targets, ws);
        ctc_kernel<<<B, 64, 0, stream>>>(ws, targets, input_lens, target_lens, out);
    } else {
        ctc_direct_kernel<<<B, 64, 0, stream>>>(logp, targets, input_lens, target_lens, out);
    }
}

// Round 4
// 232.690 us; speedup vs baseline: 1.1769x; 1.0147x over previous
//
#include <hip/hip_runtime.h>
#include <hip/hip_fp16.h>

// CTC loss forward, sum over batch. Linear-domain alpha recurrence with
// periodic exact power-of-2 rescaling (esum tracks the log-scale).
//
// Kernel A: compact + exponentiate emissions into fp16:
//           ws[b][t][l] = (half)exp(logp[t,b,ext[l]] + OFF)
//           (p' in [~0.007, ~60] for log-softmax inputs -> fp16-safe)
// Kernel B: one wave per batch element; lane owns 4 consecutive trellis
//           positions; cross-lane via DPP wave_shr:1; 8B fp16x4 emission
//           loads prefetched PFD deep; __launch_bounds__(64,1) unlocks the
//           VGPR budget so the prefetch ring stays register-resident.

constexpr int T = 1000, B = 32, C = 1000, S = 100;
constexpr int L = 2 * S + 1;      // 201
constexpr int RS = 204;           // padded row stride (halves), 8B-aligned rows (408B)
constexpr int PFD = 32;           // prefetch depth
constexpr int RROWS = T + PFD;    // pad rows so the prefetch stays in-bounds
constexpr float OFF = 7.0f;       // emission log-offset: keeps per-step growth near 1.0
constexpr float LOG2E = 1.4426950408889634f;
constexpr float LN2 = 0.6931471805599453f;

// DPP wave_shr:1 — lane i reads lane i-1; lane 0 gets 0 (bound_ctrl).
__device__ __forceinline__ float dpp_shr1(float x) {
    return __int_as_float(
        __builtin_amdgcn_update_dpp(0, __float_as_int(x), 0x138, 0xF, 0xF, true));
}

// Wave-wide max of NONNEGATIVE values via gfx9 DPP ladder; result uniform (SGPR).
__device__ __forceinline__ float wave_max_nonneg(float x) {
#define DPP_MAX(ctrl)                                                        \
    x = fmaxf(x, __int_as_float(__builtin_amdgcn_update_dpp(                 \
                     0, __float_as_int(x), (ctrl), 0xF, 0xF, true)))
    DPP_MAX(0x111);  // row_shr:1
    DPP_MAX(0x112);  // row_shr:2
    DPP_MAX(0x114);  // row_shr:4
    DPP_MAX(0x118);  // row_shr:8  -> lane15/31/47/63 hold 16-lane maxes
    DPP_MAX(0x142);  // row_bcast15 -> lane31/63 hold 32-lane maxes
    DPP_MAX(0x143);  // row_bcast31 -> lane63 holds wave max
#undef DPP_MAX
    return __int_as_float(__builtin_amdgcn_readlane(__float_as_int(x), 63));
}

// 4 packed halves (as uint2, 8B) -> 4 floats
__device__ __forceinline__ void h4_to_f(const uint2 q, float& x, float& y,
                                        float& z, float& w) {
    const __half2 lo = *reinterpret_cast<const __half2*>(&q.x);
    const __half2 hi = *reinterpret_cast<const __half2*>(&q.y);
    const float2 f01 = __half22float2(lo);
    const float2 f23 = __half22float2(hi);
    x = f01.x; y = f01.y; z = f23.x; w = f23.y;
}

// ---------------- Kernel A: staging ----------------
__global__ void stage_kernel(const float* __restrict__ logp,
                             const int* __restrict__ targets,
                             __half* __restrict__ ws) {
    const int t = blockIdx.x;
    const int b = blockIdx.y;
    __shared__ float row[C];
    const float* src = logp + ((size_t)t * B + b) * C;
    const int tid = threadIdx.x;
    if (tid < C / 4) {
        ((float4*)row)[tid] = ((const float4*)src)[tid];
    }
    __syncthreads();
    if (tid < RS) {
        float p;
        if (tid < L) {
            const int c = (tid & 1) ? targets[b * S + (tid >> 1)] : 0;
            p = exp2f((row[c] + OFF) * LOG2E);
        } else {
            p = 0.0f;  // pad columns 201..203 -> dead (keeps lane-50 a1..a3 == 0)
        }
        ws[((size_t)b * RROWS + t) * RS + tid] = __float2half(p);
    }
}

// ---------------- Kernel B: recurrence ----------------
__global__ void __launch_bounds__(64, 1) ctc_kernel(
        const __half* __restrict__ ws, const int* __restrict__ targets,
        const int* __restrict__ input_lens, const int* __restrict__ target_lens,
        float* __restrict__ out) {
    const int b = blockIdx.x;
    const int lane = threadIdx.x;
    // lanes 0..50 own positions 4*lane..4*lane+3; lanes 51..63 are dead (clamped col)
    const int col = (lane <= 50) ? 4 * lane : 200;
    const int Tb = input_lens[b];
    const int tl = target_lens[b];
    const __half* pw = ws + (size_t)b * RROWS * RS;

    // Skip-transition masks. Even positions are blanks -> no skip ever, so only
    // the two odd positions (col+1, col+3) need masks.
    float m1 = 0.f, m3 = 0.f;
    if (lane <= 50) {
        const int l1 = col + 1;  // odd
        if (l1 >= 3 && l1 < L) {
            const int s = (l1 - 1) >> 1;
            if (targets[b * S + s] != targets[b * S + s - 1]) m1 = 1.f;
        }
        const int l3 = col + 3;  // odd
        if (l3 >= 3 && l3 < L) {
            const int s = (l3 - 1) >> 1;
            if (targets[b * S + s] != targets[b * S + s - 1]) m3 = 1.f;
        }
    }

    // init at t=0: alpha[0] = p(blank), alpha[1] = p(tgt0), rest 0
    float a0 = 0.f, a1 = 0.f, a2 = 0.f, a3 = 0.f;
    {
        const uint2 q0 = *(const uint2*)(pw + col);
        float x, y, z, w;
        h4_to_f(q0, x, y, z, w);
        if (lane == 0) { a0 = x; a1 = y; }
    }
    int esum = 0;

    // Dead-lane invariant: lane 50's cols 201..203 are staged 0, so its
    // a1,a2,a3 stay exactly 0; lanes 51+ therefore receive zeros via DPP and
    // stay 0. Lane 0 receives 0 via bound_ctrl. No masking needed in the step.
    // Even positions (col, col+2) are blanks -> no skip term.
#define CTC_STEP(Q_)                                  \
    do {                                              \
        float px, py, pz, pwv;                        \
        h4_to_f((Q_), px, py, pz, pwv);               \
        const float am1 = dpp_shr1(a3);               \
        const float s01 = a0 + a1;                    \
        const float s23 = a2 + a3;                    \
        const float n0 = (a0 + am1) * px;             \
        const float n1 = fmaf(am1, m1, s01) * py;     \
        const float n2 = (a1 + a2) * pz;              \
        const float n3 = fmaf(a1, m3, s23) * pwv;     \
        a0 = n0; a1 = n1; a2 = n2; a3 = n3;           \
    } while (0)

#define CTC_RESCALE()                                                          \
    do {                                                                       \
        const float mx = wave_max_nonneg(fmaxf(fmaxf(a0, a1), fmaxf(a2, a3))); \
        const unsigned bits = __float_as_uint(mx);                             \
        if (bits != 0u) {                                                      \
            const int e = (int)((bits >> 23) & 0xFFu) - 127;                   \
            const float sc = __uint_as_float((unsigned)(127 - e) << 23);       \
            a0 *= sc; a1 *= sc; a2 *= sc; a3 *= sc;                            \
            esum += e;                                                         \
        }                                                                      \
    } while (0)

    // prefetch ring: P[i] holds emission row (as 4 packed halves) for step t+i
    uint2 P[PFD];
    {
        const __half* pf0 = pw + (size_t)RS + col;
#pragma unroll
        for (int i = 0; i < PFD; ++i) P[i] = *(const uint2*)(pf0 + (size_t)i * RS);
    }
    const __half* pf = pw + (size_t)(PFD + 1) * RS + col;  // next row to prefetch

    int t = 1;
    while (t + PFD <= Tb) {
#pragma unroll
        for (int i = 0; i < PFD; ++i) {
            const uint2 q = P[i];
            P[i] = *(const uint2*)pf;   // prefetch PFD steps ahead
            pf += RS;
            CTC_STEP(q);
            if (i == 15) CTC_RESCALE();  // keep 16-step rescale cadence
        }
        CTC_RESCALE();
        t += PFD;
    }
    // tail (< PFD steps), uniform predicates
    {
        const int rem = Tb - t;  // steps remaining: t..Tb-1
#pragma unroll
        for (int i = 0; i < PFD; ++i) {
            if (i < rem) {
                const uint2 q = P[i];
                CTC_STEP(q);
                if (i == 15) CTC_RESCALE();  // safety: bound unrescaled run
            }
        }
    }
#undef CTC_STEP

    // final: sum alpha at positions 2*tl and 2*tl-1
    const int e1 = 2 * tl, e2 = 2 * tl - 1;
    float contrib = 0.f;
    if (lane <= 50) {
        if (col + 0 == e1 || col + 0 == e2) contrib += a0;
        if (col + 1 == e1 || col + 1 == e2) contrib += a1;
        if (col + 2 == e1 || col + 2 == e2) contrib += a2;
        if (col + 3 == e1 || col + 3 == e2) contrib += a3;
    }
#pragma unroll
    for (int off = 32; off; off >>= 1) contrib += __shfl_xor(contrib, off);

    if (lane == 0) {
        const float logalpha = logf(contrib) + (float)esum * LN2 - OFF * (float)Tb;
        float loss = -logalpha;
        if (!(loss < 0.5e30f)) loss = 0.f;  // zero_infinity (also catches NaN/inf)
        atomicAdd(out, loss);
    }
}

// ---------------- Fallback: direct gather (if ws too small) ----------------
__global__ void __launch_bounds__(64, 1) ctc_direct_kernel(
        const float* __restrict__ logp, const int* __restrict__ targets,
        const int* __restrict__ input_lens, const int* __restrict__ target_lens,
        float* __restrict__ out) {
    const int b = blockIdx.x;
    const int lane = threadIdx.x;
    const int col = (lane <= 50) ? 4 * lane : 200;
    const int Tb = input_lens[b];
    const int tl = target_lens[b];

    int cc[4]; float mm[4], pm[4];
#pragma unroll
    for (int i = 0; i < 4; ++i) {
        const int l = col + i;
        const bool real = (lane <= 50) && (l < L);
        pm[i] = real ? 1.f : 0.f;
        cc[i] = real ? ((l & 1) ? targets[b * S + (l >> 1)] : 0) : 0;
        float mk = 0.f;
        if (real && (l & 1) && l >= 3) {
            const int s = (l - 1) >> 1;
            if (targets[b * S + s] != targets[b * S + s - 1]) mk = 1.f;
        }
        mm[i] = mk;
    }
    const float m1 = mm[1], m3 = mm[3];

    float a0 = 0.f, a1 = 0.f, a2 = 0.f, a3 = 0.f;
    {
        const float* rowp = logp + (size_t)b * C;
        const float p0 = pm[0] * exp2f((rowp[cc[0]] + OFF) * LOG2E);
        const float p1 = pm[1] * exp2f((rowp[cc[1]] + OFF) * LOG2E);
        if (lane == 0) { a0 = p0; a1 = p1; }
    }
    int esum = 0;

    for (int t = 1; t < Tb; ++t) {
        const float* rowp = logp + ((size_t)t * B + b) * C;
        const float p0 = pm[0] * exp2f((rowp[cc[0]] + OFF) * LOG2E);
        const float p1 = pm[1] * exp2f((rowp[cc[1]] + OFF) * LOG2E);
        const float p2 = pm[2] * exp2f((rowp[cc[2]] + OFF) * LOG2E);
        const float p3 = pm[3] * exp2f((rowp[cc[3]] + OFF) * LOG2E);
        const float am1 = dpp_shr1(a3);
        const float n0 = (a0 + am1) * p0;
        const float n1 = fmaf(am1, m1, a0 + a1) * p1;
        const float n2 = (a1 + a2) * p2;
        const float n3 = fmaf(a1, m3, a2 + a3) * p3;
        a0 = n0; a1 = n1; a2 = n2; a3 = n3;
        if ((t & 15) == 0) {
            const float mx = wave_max_nonneg(fmaxf(fmaxf(a0, a1), fmaxf(a2, a3)));
            const unsigned bits = __float_as_uint(mx);
            if (bits != 0u) {
                const int e = (int)((bits >> 23) & 0xFFu) - 127;
                const float sc = __uint_as_float((unsigned)(127 - e) << 23);
                a0 *= sc; a1 *= sc; a2 *= sc; a3 *= sc;
                esum += e;
            }
        }
    }

    const int e1 = 2 * tl, e2 = 2 * tl - 1;
    float contrib = 0.f;
    if (lane <= 50) {
        if (col + 0 == e1 || col + 0 == e2) contrib += a0;
        if (col + 1 == e1 || col + 1 == e2) contrib += a1;
        if (col + 2 == e1 || col + 2 == e2) contrib += a2;
        if (col + 3 == e1 || col + 3 == e2) contrib += a3;
    }
#pragma unroll
    for (int off = 32; off; off >>= 1) contrib += __shfl_xor(contrib, off);
    if (lane == 0) {
        const float logalpha = logf(contrib) + (float)esum * LN2 - OFF * (float)Tb;
        float loss = -logalpha;
        if (!(loss < 0.5e30f)) loss = 0.f;
        atomicAdd(out, loss);
    }
}

extern "C" void kernel_launch(void* const* d_in, const int* in_sizes, int n_in,
                              void* d_out, int out_size, void* d_ws, size_t ws_size,
                              hipStream_t stream) {
    const float* logp = (const float*)d_in[0];
    const int* targets = (const int*)d_in[1];
    const int* input_lens = (const int*)d_in[2];
    const int* target_lens = (const int*)d_in[3];
    float* out = (float*)d_out;
    __half* ws = (__half*)d_ws;

    hipMemsetAsync(d_out, 0, sizeof(float), stream);

    const size_t ws_needed = (size_t)B * RROWS * RS * sizeof(__half);
    if (ws_size >= ws_needed) {
        dim3 gA(T, B);
        stage_kernel<<<gA, 256, 0, stream>>>(logp, targets, ws);
        ctc_kernel<<<B, 64, 0, stream>>>(ws, targets, input_lens, target_lens, out);
    } else {
        ctc_direct_kernel<<<B, 64, 0, stream>>>(logp, targets, input_lens, target_lens, out);
    }
}